// Round 3
// baseline (3447.031 us; speedup 1.0000x reference)
//
#include <hip/hip_runtime.h>
#include <cstdint>

#define NB 4
#define NPTS 4096
#define KNN 20
#define BN (NB*NPTS)   // 16384
#define NPART 8
#define SLOTS 24
#define TIEBIT (1<<20)

__device__ __forceinline__ float lrelu_f(float x) { return x > 0.f ? x : 0.2f * x; }

__device__ __forceinline__ float med3f(float c, float lo, float hi) {
#if defined(__has_builtin)
#if __has_builtin(__builtin_amdgcn_fmed3f)
  return __builtin_amdgcn_fmed3f(c, lo, hi);
#else
  return fminf(fmaxf(c, lo), hi);
#endif
#else
  return fminf(fmaxf(c, lo), hi);
#endif
}

// shared ranking key: xx_j - 2*dot(q, x_j)  (qq omitted: constant per query).
// MUST be bit-identical between pass1 and recovery -> one inlined fn, explicit fmaf.
template<int CH, int CHP>
__device__ __forceinline__ float knn_key(const float* __restrict__ xb,
                                         const float* __restrict__ xxb,
                                         int j, const float* qf) {
  const float* xj = xb + (size_t)j*CHP;
  if (CH == 3) {
    float dot = qf[0]*xj[0];
    dot = fmaf(qf[1], xj[1], dot);
    dot = fmaf(qf[2], xj[2], dot);
    return fmaf(-2.f, dot, xxb[j]);
  } else {
    float d0 = 0.f, d1 = 0.f, d2 = 0.f, d3 = 0.f;
    #pragma unroll
    for (int c = 0; c < CH; c += 4) {
      d0 = fmaf(qf[c+0], xj[c+0], d0);
      d1 = fmaf(qf[c+1], xj[c+1], d1);
      d2 = fmaf(qf[c+2], xj[c+2], d2);
      d3 = fmaf(qf[c+3], xj[c+3], d3);
    }
    return fmaf(-2.f, (d0+d1)+(d2+d3), xxb[j]);
  }
}

// ---------------------------------------------------------------- prep weights
__global__ __launch_bounds__(256) void prep_weights(
    const float* __restrict__ wdg1, const float* __restrict__ bdg1,
    const float* __restrict__ wdg2,
    const float* __restrict__ wsn1, const float* __restrict__ bsn1,
    const float* __restrict__ w3,
    float* __restrict__ WEFF1, float* __restrict__ WT2,
    float* __restrict__ WEFF2, float* __restrict__ W3T,
    float* __restrict__ BUV1, float* __restrict__ BUV2)
{
  int i = blockIdx.x * 256 + threadIdx.x;
  if (i < 512*1024) { int c = i >> 10, o = i & 1023; W3T[i] = w3[o*512 + c]; }
  if (i < 64*256) {
    int c = i >> 8, r = i & 255;
    WEFF1[i] = (r < 128) ? wdg1[r*128 + c]
                         : (wdg1[(r-128)*128 + 64 + c] - wdg1[(r-128)*128 + c]);
  }
  if (i < 128*128) { int c = i >> 7, o = i & 127; WT2[i] = wdg2[o*128 + c]; }
  if (i < 128*512) {
    int c = i >> 9, r = i & 511;
    WEFF2[i] = (r < 256) ? wsn1[r*256 + c]
                         : (wsn1[(r-256)*256 + 128 + c] - wsn1[(r-256)*256 + c]);
  }
  if (i < 256) BUV1[i] = (i < 128) ? 0.f : bdg1[i-128];
  if (i < 512) BUV2[i] = (i < 256) ? 0.f : bsn1[i-256];
}

// ---------------------------------------------------------------- pack xyz (point-major, padded) + sqnorm
__global__ __launch_bounds__(256) void pack_xyz(
    const float* __restrict__ xyz, float* __restrict__ XTP, float* __restrict__ XXP)
{
  int i = blockIdx.x * 256 + threadIdx.x;
  if (i >= BN) return;
  int b = i >> 12, n = i & (NPTS-1);
  const float* p = xyz + (size_t)b*3*NPTS;
  float x = p[n], y = p[NPTS+n], z = p[2*NPTS+n];
  XTP[i*4+0]=x; XTP[i*4+1]=y; XTP[i*4+2]=z; XTP[i*4+3]=0.f;
  XXP[i] = x*x + y*y + z*z;
}

// ---------------------------------------------------------------- conv1 + conv2 fused (3->64->64), point-major out + sqnorm
__global__ __launch_bounds__(256) void conv12(
    const float* __restrict__ xyz,
    const float* __restrict__ w1, const float* __restrict__ b1,
    const float* __restrict__ w2, const float* __restrict__ b2,
    float* __restrict__ XT2, float* __restrict__ XX2)
{
  __shared__ float w2t[64*65];
  __shared__ float h1s[4][64];
  int tid = threadIdx.x;
  for (int i = tid; i < 4096; i += 256) {
    int o = i >> 6, c = i & 63;
    w2t[c*65 + o] = w2[i];
  }
  int g = tid >> 6, o = tid & 63;
  int pt = blockIdx.x*4 + g;
  int b = pt >> 12, n = pt & (NPTS-1);
  const float* p = xyz + (size_t)b*3*NPTS;
  float x = p[n], y = p[NPTS+n], z = p[2*NPTS+n];
  float h1 = b1[o] + w1[o*3]*x + w1[o*3+1]*y + w1[o*3+2]*z;
  h1 = lrelu_f(h1);
  __syncthreads();
  h1s[g][o] = h1;
  __syncthreads();
  float acc = b2[o];
  #pragma unroll
  for (int c = 0; c < 64; ++c) acc = fmaf(w2t[c*65+o], h1s[g][c], acc);
  acc = lrelu_f(acc);
  XT2[(size_t)pt*64 + o] = acc;
  float v = acc*acc;
  #pragma unroll
  for (int s = 32; s > 0; s >>= 1) v += __shfl_down(v, s, 64);
  if (o == 0) XX2[pt] = v;
}

// ---------------------------------------------------------------- knn pass1: top-20 DISTANCES only (med3 sorted-insert)
template<int CH, int CHP>
__global__ __launch_bounds__(256, 2) void knn_pass1(
    const float* __restrict__ XT, const float* __restrict__ XX,
    float* __restrict__ PD)
{
  int b = blockIdx.x >> 4;
  int q = blockIdx.x * 256 + threadIdx.x;
  const float* xq = XT + (size_t)q*CHP;
  float qf[CH];
  #pragma unroll
  for (int c = 0; c < CH; ++c) qf[c] = xq[c];
  #pragma unroll
  for (int c = 0; c < CH; ++c) asm volatile("" : "+v"(qf[c]));  // pin: no remat/spill
  const float* xb  = XT + ((size_t)(b << 12))*CHP;
  const float* xxb = XX + ((size_t)(b << 12));
  float bd[KNN];
  #pragma unroll
  for (int t = 0; t < KNN; ++t) bd[t] = 1e30f;
  int j0 = blockIdx.y * (NPTS/NPART), j1 = j0 + (NPTS/NPART);
  for (int j = j0; j < j1; ++j) {
    float cd = knn_key<CH,CHP>(xb, xxb, j, qf);
    #pragma unroll
    for (int t = KNN-1; t >= 1; --t) bd[t] = med3f(cd, bd[t-1], bd[t]);
    bd[0] = fminf(bd[0], cd);
  }
  size_t o = ((size_t)blockIdx.y*BN + q)*KNN;
  #pragma unroll
  for (int t = 0; t < KNN; ++t) PD[o+t] = bd[t];
}

// ---------------------------------------------------------------- merge partial lists -> threshold + tie quota
__global__ __launch_bounds__(256) void knn_merge_thr(
    const float* __restrict__ PD, float* __restrict__ THR, int* __restrict__ QUO)
{
  int q = blockIdx.x*256 + threadIdx.x;
  float bd[KNN];
  #pragma unroll
  for (int t = 0; t < KNN; ++t) bd[t] = 1e30f;
  for (int p = 0; p < NPART; ++p) {
    size_t o = ((size_t)p*BN + q)*KNN;
    #pragma unroll
    for (int t = 0; t < KNN; ++t) {
      float cd = PD[o+t];
      if (cd >= bd[KNN-1]) break;   // partition list sorted ascending
      #pragma unroll
      for (int t2 = KNN-1; t2 >= 1; --t2) bd[t2] = med3f(cd, bd[t2-1], bd[t2]);
      bd[0] = fminf(bd[0], cd);
    }
  }
  float thr = bd[KNN-1];
  int m = 0;
  #pragma unroll
  for (int t = 0; t < KNN; ++t) m += (bd[t] < thr) ? 1 : 0;
  THR[q] = thr;
  QUO[q] = KNN - m;
}

// ---------------------------------------------------------------- knn recovery: emit indices with d<thr, plus ties up to quota
template<int CH, int CHP>
__global__ __launch_bounds__(256, 2) void knn_recover(
    const float* __restrict__ XT, const float* __restrict__ XX,
    const float* __restrict__ THR, const int* __restrict__ QUO,
    int* __restrict__ OUTB, int* __restrict__ CNT)
{
  int b = blockIdx.x >> 4;
  int q = blockIdx.x * 256 + threadIdx.x;
  const float* xq = XT + (size_t)q*CHP;
  float qf[CH];
  #pragma unroll
  for (int c = 0; c < CH; ++c) qf[c] = xq[c];
  #pragma unroll
  for (int c = 0; c < CH; ++c) asm volatile("" : "+v"(qf[c]));
  const float* xb  = XT + ((size_t)(b << 12))*CHP;
  const float* xxb = XX + ((size_t)(b << 12));
  float thr = THR[q];
  int quo = QUO[q];
  int part = blockIdx.y;
  int j0 = part * (NPTS/NPART), j1 = j0 + (NPTS/NPART);
  int cnt = 0, tcnt = 0;
  size_t base = ((size_t)q*NPART + part)*SLOTS;
  for (int j = j0; j < j1; ++j) {
    float d = knn_key<CH,CHP>(xb, xxb, j, qf);
    bool st = d < thr;
    bool ti = (d == thr) && (tcnt < quo);
    if ((st || ti) && cnt < SLOTS)
      OUTB[base + cnt] = ti ? (j | TIEBIT) : j;
    cnt  += (st || ti) ? 1 : 0;
    tcnt += ti ? 1 : 0;
  }
  CNT[q*NPART + part] = (cnt < SLOTS) ? cnt : SLOTS;
}

// ---------------------------------------------------------------- stitch: stricts (all), then ties in (part, j) order
__global__ __launch_bounds__(256) void knn_stitch(
    const int* __restrict__ OUTB, const int* __restrict__ CNT,
    int* __restrict__ IDX)
{
  int q = blockIdx.x*256 + threadIdx.x;
  int cnt = 0;
  for (int p = 0; p < NPART; ++p) {
    int c = CNT[q*NPART + p];
    size_t base = ((size_t)q*NPART + p)*SLOTS;
    for (int e = 0; e < c; ++e) {
      int v = OUTB[base + e];
      if (!(v & TIEBIT)) { if (cnt < KNN) IDX[(size_t)q*KNN + cnt] = v; cnt++; }
    }
  }
  for (int p = 0; p < NPART; ++p) {
    int c = CNT[q*NPART + p];
    size_t base = ((size_t)q*NPART + p)*SLOTS;
    for (int e = 0; e < c; ++e) {
      int v = OUTB[base + e];
      if (v & TIEBIT) { if (cnt < KNN) IDX[(size_t)q*KNN + cnt] = v & (TIEBIT-1); cnt++; }
    }
  }
  for (; cnt < KNN; ++cnt) IDX[(size_t)q*KNN + cnt] = q & (NPTS-1);  // self-pad (max-pool no-op)
}

// ---------------------------------------------------------------- generic point-major GEMM: Out = act(Wt^T-ish @ F + bias)
template<bool LRELU_, bool CM>
__global__ __launch_bounds__(256) void gemm_pm(
    const float* __restrict__ Wt, int Mtot, int KT,
    const float* __restrict__ F, int fstride, int foff,
    const float* __restrict__ bias,
    float* __restrict__ Out, int ostride, int ooff)
{
  __shared__ float Ws[16][128];
  __shared__ float Fs[16][132];
  int tid = threadIdx.x;
  int rg = tid & 15, cg = tid >> 4;
  int rt = blockIdx.y * 128, ct = blockIdx.x * 128;
  float acc[8][8];
  #pragma unroll
  for (int u = 0; u < 8; ++u)
    #pragma unroll
    for (int v = 0; v < 8; ++v) acc[u][v] = 0.f;

  for (int c0 = 0; c0 < KT; c0 += 16) {
    #pragma unroll
    for (int i = 0; i < 8; ++i) {
      int idx = tid + i*256;
      int kk = idx >> 7, r = idx & 127;
      Ws[kk][r] = Wt[(size_t)(c0+kk)*Mtot + rt + r];
    }
    #pragma unroll
    for (int i = 0; i < 8; ++i) {
      int idx = tid + i*256;
      int kk = idx & 15, p = idx >> 4;
      Fs[kk][p] = F[(size_t)(ct+p)*fstride + foff + c0 + kk];
    }
    __syncthreads();
    #pragma unroll
    for (int kk = 0; kk < 16; ++kk) {
      float a[8], bb[8];
      #pragma unroll
      for (int u = 0; u < 8; ++u) a[u] = Ws[kk][rg*8+u];
      #pragma unroll
      for (int v = 0; v < 8; ++v) bb[v] = Fs[kk][cg*8+v];
      #pragma unroll
      for (int u = 0; u < 8; ++u)
        #pragma unroll
        for (int v = 0; v < 8; ++v) acc[u][v] = fmaf(a[u], bb[v], acc[u][v]);
    }
    __syncthreads();
  }
  #pragma unroll
  for (int u = 0; u < 8; ++u) {
    float bv = bias[rt + rg*8 + u];
    #pragma unroll
    for (int v = 0; v < 8; ++v) {
      float val = acc[u][v] + bv;
      if (LRELU_) val = lrelu_f(val);
      acc[u][v] = val;
    }
  }
  if (CM) {
    int b = ct >> 12, n0 = ct & (NPTS-1);
    #pragma unroll
    for (int u = 0; u < 8; ++u) {
      int r = rt + rg*8 + u;
      float* po = Out + ((size_t)b*Mtot + r)*NPTS + n0 + cg*8;
      #pragma unroll
      for (int v = 0; v < 8; ++v) po[v] = acc[u][v];
    }
  } else {
    #pragma unroll
    for (int v = 0; v < 8; ++v) {
      int pt = ct + cg*8 + v;
      float* po = Out + (size_t)pt*ostride + ooff + rt + rg*8;
      #pragma unroll
      for (int u = 0; u < 8; ++u) po[u] = acc[u][v];
    }
  }
}

// ---------------------------------------------------------------- gather H1 = lrelu(U1[j] + V1[n]) (per batch), also x1 = max_k
__global__ __launch_bounds__(256) void gather_h1(
    const float* __restrict__ UV1, const int* __restrict__ IDXF,
    float* __restrict__ H1, float* __restrict__ FEAT, int batch)
{
  int n = blockIdx.x;
  int tid = threadIdx.x;
  size_t ptg = (size_t)batch*NPTS + n;
  __shared__ int js[KNN];
  if (tid < KNN) js[tid] = IDXF[ptg*KNN + tid];
  __syncthreads();
  int c = tid & 127, k0 = tid >> 7;
  float vv = UV1[ptg*256 + 128 + c];
  const float* Ub = UV1 + ((size_t)batch*NPTS)*256;
  float* Hb = H1 + (size_t)n*KNN*128;
  float mx = -1e30f;
  for (int kk = k0; kk < KNN; kk += 2) {
    int j = js[kk];
    float h = lrelu_f(Ub[(size_t)j*256 + c] + vv);
    Hb[kk*128 + c] = h;
    mx = fmaxf(mx, h);
  }
  __shared__ float m2[2][128];
  m2[k0][c] = mx;
  __syncthreads();
  if (tid < 128) FEAT[ptg*512 + tid] = fmaxf(m2[0][tid], m2[1][tid]);
}

// ---------------------------------------------------------------- dg2 GEMM with lrelu + 20-group max epilogue -> x2
__global__ __launch_bounds__(256) void dg2_gemm(
    const float* __restrict__ Wt2, const float* __restrict__ H1,
    const float* __restrict__ bias, float* __restrict__ FEAT, int batch)
{
  __shared__ float Ws[16][128];
  __shared__ float Fs[16][84];
  __shared__ float mb[16][132];
  int tid = threadIdx.x;
  int rg = tid & 15, cg = tid >> 4;
  int ct = blockIdx.x * 80;
  float acc[8][5];
  #pragma unroll
  for (int u = 0; u < 8; ++u)
    #pragma unroll
    for (int v = 0; v < 5; ++v) acc[u][v] = 0.f;

  for (int c0 = 0; c0 < 128; c0 += 16) {
    #pragma unroll
    for (int i = 0; i < 8; ++i) {
      int idx = tid + i*256;
      int kk = idx >> 7, r = idx & 127;
      Ws[kk][r] = Wt2[(c0+kk)*128 + r];
    }
    #pragma unroll
    for (int i = 0; i < 5; ++i) {
      int idx = tid + i*256;
      int kk = idx & 15, p = idx >> 4;
      Fs[kk][p] = H1[(size_t)(ct+p)*128 + c0 + kk];
    }
    __syncthreads();
    #pragma unroll
    for (int kk = 0; kk < 16; ++kk) {
      float a[8], bb[5];
      #pragma unroll
      for (int u = 0; u < 8; ++u) a[u] = Ws[kk][rg*8+u];
      #pragma unroll
      for (int v = 0; v < 5; ++v) bb[v] = Fs[kk][cg*5+v];
      #pragma unroll
      for (int u = 0; u < 8; ++u)
        #pragma unroll
        for (int v = 0; v < 5; ++v) acc[u][v] = fmaf(a[u], bb[v], acc[u][v]);
    }
    __syncthreads();
  }
  #pragma unroll
  for (int u = 0; u < 8; ++u) {
    int r = rg*8+u;
    float bv = bias[r];
    float m = -1e30f;
    #pragma unroll
    for (int v = 0; v < 5; ++v) m = fmaxf(m, lrelu_f(acc[u][v] + bv));
    mb[cg][r] = m;
  }
  __syncthreads();
  if ((cg & 3) == 0) {
    int g = cg >> 2;
    size_t pt = (size_t)batch*NPTS + blockIdx.x*4 + g;
    #pragma unroll
    for (int u = 0; u < 8; ++u) {
      int r = rg*8+u;
      float m = fmaxf(fmaxf(mb[cg][r], mb[cg+1][r]), fmaxf(mb[cg+2][r], mb[cg+3][r]));
      FEAT[pt*512 + 128 + r] = m;
    }
  }
}

// ---------------------------------------------------------------- sn block: x3 = max_k lrelu(U2[j] + V2[n])
__global__ __launch_bounds__(256) void sn_gather(
    const float* __restrict__ UV2, const int* __restrict__ IDXX,
    float* __restrict__ FEAT)
{
  int tid = threadIdx.x;   // channel 0..255
  int p0 = blockIdx.x * 4;
  for (int pp = 0; pp < 4; ++pp) {
    size_t pt = (size_t)(p0 + pp);
    size_t bb = (size_t)((p0+pp) >> 12) << 12;
    float v = UV2[pt*512 + 256 + tid];
    float m = -1e30f;
    for (int k = 0; k < KNN; ++k) {
      int j = IDXX[pt*KNN + k];
      float h = lrelu_f(UV2[(bb + j)*512 + tid] + v);
      m = fmaxf(m, h);
    }
    FEAT[pt*512 + 256 + tid] = m;
  }
}

// ---------------------------------------------------------------- farthest point sampling (per batch)
__global__ __launch_bounds__(256) void fps_kernel(
    const float* __restrict__ xyz, int* __restrict__ SIDX)
{
  int b = blockIdx.x, tid = threadIdx.x;
  const float* p = xyz + (size_t)b*3*NPTS;
  __shared__ float dist[NPTS];
  __shared__ float rmax[256];
  __shared__ int   ridx[256];
  __shared__ int   curf;
  for (int i = tid; i < NPTS; i += 256) dist[i] = 1e10f;
  if (tid == 0) curf = 0;
  __syncthreads();
  for (int it = 0; it < 32; ++it) {
    int far = curf;
    if (tid == 0) SIDX[b*32 + it] = far;
    float cx = p[far], cy = p[NPTS+far], cz = p[2*NPTS+far];
    float lm = -1e30f; int li = 0;
    for (int i = tid; i < NPTS; i += 256) {
      float dx = p[i]-cx, dy = p[NPTS+i]-cy, dz = p[2*NPTS+i]-cz;
      float d = dx*dx + dy*dy + dz*dz;
      float dm = fminf(dist[i], d);
      dist[i] = dm;
      if (dm > lm) { lm = dm; li = i; }
    }
    rmax[tid] = lm; ridx[tid] = li;
    __syncthreads();
    for (int s = 128; s > 0; s >>= 1) {
      if (tid < s) {
        float a = rmax[tid], bv = rmax[tid+s];
        int ia = ridx[tid], ib = ridx[tid+s];
        if (bv > a || (bv == a && ib < ia)) { rmax[tid] = bv; ridx[tid] = ib; }
      }
      __syncthreads();
    }
    if (tid == 0) curf = ridx[0];
    __syncthreads();
  }
}

// ---------------------------------------------------------------- k-farthest (8) among 32 samples
__global__ __launch_bounds__(128) void kfn_kernel(
    const float* __restrict__ xyz, const int* __restrict__ SIDX,
    int* __restrict__ NIDX)
{
  int tid = threadIdx.x;     // 0..127
  int b = tid >> 5, i = tid & 31;
  const float* p = xyz + (size_t)b*3*NPTS;
  __shared__ float sx[4][32], sy[4][32], sz[4][32];
  {
    int si = SIDX[b*32 + i];
    sx[b][i] = p[si]; sy[b][i] = p[NPTS+si]; sz[b][i] = p[2*NPTS+si];
  }
  __syncthreads();
  float xi = sx[b][i], yi = sy[b][i], zi = sz[b][i];
  float xxi = xi*xi + yi*yi + zi*zi;
  float bd[8]; int bi_[8];
  #pragma unroll
  for (int t = 0; t < 8; ++t) { bd[t] = -1e30f; bi_[t] = 0; }
  for (int j = 0; j < 32; ++j) {
    float xj = sx[b][j], yj = sy[b][j], zj = sz[b][j];
    float xxj = xj*xj + yj*yj + zj*zj;
    float d = xxi - 2.f*(xi*xj + yi*yj + zi*zj) + xxj;
    if (d > bd[7]) {
      float cd = d; int ci = j;
      #pragma unroll
      for (int t = 0; t < 8; ++t) {
        bool sw = bd[t] < cd;       // descending
        float nv = sw ? cd : bd[t];
        int   ni = sw ? ci : bi_[t];
        float ov = sw ? bd[t] : cd;
        int   oi = sw ? bi_[t] : ci;
        bd[t] = nv; bi_[t] = ni; cd = ov; ci = oi;
      }
    }
  }
  size_t o = (size_t)(b*32 + i)*8;
  #pragma unroll
  for (int t = 0; t < 8; ++t) NIDX[o+t] = bi_[t];
}

// ---------------------------------------------------------------- triplet terms
__global__ __launch_bounds__(256) void trip_kernel(
    const float* __restrict__ es0, const float* __restrict__ et0,
    const int* __restrict__ SIDX, const int* __restrict__ NIDX,
    float* __restrict__ ACC)
{
  int bi_ = blockIdx.x; int b = bi_ >> 5;
  int tid = threadIdx.x;
  __shared__ int js[8];
  __shared__ int ssi;
  if (tid == 0) ssi = SIDX[bi_];
  if (tid < 8) js[tid] = SIDX[b*32 + NIDX[bi_*8 + tid]];
  __syncthreads();
  int si = ssi;
  const float* es = es0 + (size_t)b*1024*NPTS;
  const float* et = et0 + (size_t)b*1024*NPTS;
  float sp = 0.f, sn = 0.f;
  for (int c = tid; c < 1024; c += 256) {
    const float* erow = et + (size_t)c*NPTS;
    float s = es[(size_t)c*NPTS + si];
    float d0 = s - erow[si]; sp += d0*d0;
    #pragma unroll
    for (int t = 0; t < 8; ++t) { float d1 = s - erow[js[t]]; sn += d1*d1; }
  }
  __shared__ float r1[256], r2[256];
  r1[tid] = sp; r2[tid] = sn; __syncthreads();
  for (int s2 = 128; s2 > 0; s2 >>= 1) {
    if (tid < s2) { r1[tid] += r1[tid+s2]; r2[tid] += r2[tid+s2]; }
    __syncthreads();
  }
  if (tid == 0) {
    float dp = r1[0] * (1.f/1024.f);
    float dn = r2[0] * (1.f/8192.f);
    float tr = fmaxf(0.f, 1.f - dn/(1.f + dp));
    atomicAdd(&ACC[0], tr);
  }
}

// ---------------------------------------------------------------- norms + mse + mae
__global__ __launch_bounds__(256) void stats_kernel(
    const float* __restrict__ es0, const float* __restrict__ et0,
    float* __restrict__ ACC)
{
  int tid = threadIdx.x;
  int p = tid & 63, g = tid >> 6;
  int pt0 = blockIdx.x * 64;
  int b = pt0 >> 12, n0 = pt0 & (NPTS-1);
  const float* es = es0 + (size_t)b*1024*NPTS + n0;
  const float* et = et0 + (size_t)b*1024*NPTS + n0;
  float ss = 0.f, tt = 0.f, sq = 0.f, ab = 0.f;
  for (int c = g; c < 1024; c += 4) {
    float s = es[(size_t)c*NPTS + p];
    float t = et[(size_t)c*NPTS + p];
    ss += s*s; tt += t*t;
    float d = s - t;
    sq += d*d; ab += fabsf(d);
  }
  __shared__ float rs[4][64], rt[4][64];
  __shared__ float red[256];
  rs[g][p] = ss; rt[g][p] = tt;
  red[tid] = sq;
  __syncthreads();
  for (int s2 = 128; s2 > 0; s2 >>= 1) {
    if (tid < s2) red[tid] += red[tid+s2];
    __syncthreads();
  }
  if (tid == 0) atomicAdd(&ACC[3], red[0]);
  __syncthreads();
  red[tid] = ab; __syncthreads();
  for (int s2 = 128; s2 > 0; s2 >>= 1) {
    if (tid < s2) red[tid] += red[tid+s2];
    __syncthreads();
  }
  if (tid == 0) atomicAdd(&ACC[4], red[0]);
  if (tid < 64) {
    float a = sqrtf(rs[0][tid]+rs[1][tid]+rs[2][tid]+rs[3][tid]) - 1.f;
    float c = sqrtf(rt[0][tid]+rt[1][tid]+rt[2][tid]+rt[3][tid]) - 1.f;
    float av = a*a, cv = c*c;
    #pragma unroll
    for (int s2 = 32; s2 > 0; s2 >>= 1) {
      av += __shfl_down(av, s2, 64);
      cv += __shfl_down(cv, s2, 64);
    }
    if (tid == 0) { atomicAdd(&ACC[1], av); atomicAdd(&ACC[2], cv); }
  }
}

// ---------------------------------------------------------------- finalize scalars
__global__ void finalize_kernel(const float* __restrict__ ACC, float* __restrict__ o3) {
  if (threadIdx.x == 0 && blockIdx.x == 0) {
    float ln1 = sqrtf(ACC[1] * (1.f/16384.f));
    float ln2 = sqrtf(ACC[2] * (1.f/16384.f));
    o3[0] = ACC[0]*(1.f/128.f) + (ln1 + ln2)*0.5f*0.03f;
    o3[1] = ACC[3] * (1.f/4194304.f);   // mean((s-t)^2)*B
    o3[2] = ACC[4] * (1.f/4194304.f);   // mean(|s-t|)*B
  }
}

// ================================================================ host
extern "C" void kernel_launch(void* const* d_in, const int* in_sizes, int n_in,
                              void* d_out, int out_size, void* d_ws, size_t ws_size,
                              hipStream_t stream) {
  (void)in_sizes; (void)n_in; (void)out_size; (void)ws_size;
  const float* src  = (const float*)d_in[0];
  const float* tgt  = (const float*)d_in[1];
  const float* w1   = (const float*)d_in[2];
  const float* b1   = (const float*)d_in[3];
  const float* w2   = (const float*)d_in[4];
  const float* b2   = (const float*)d_in[5];
  const float* wdg1 = (const float*)d_in[6];
  const float* bdg1 = (const float*)d_in[7];
  const float* wdg2 = (const float*)d_in[8];
  const float* bdg2 = (const float*)d_in[9];
  const float* wsn1 = (const float*)d_in[10];
  const float* bsn1 = (const float*)d_in[11];
  const float* w3   = (const float*)d_in[12];
  const float* b3   = (const float*)d_in[13];
  float* out = (float*)d_out;

  float* ws = (float*)d_ws;
  float* XTP  = ws;                                   // BN*4
  float* XXP  = XTP + (size_t)BN*4;                   // BN
  float* XT2  = XXP + BN;                             // BN*64
  float* XX2  = XT2 + (size_t)BN*64;                  // BN
  float* UV1  = XX2 + BN;                             // BN*256
  float* FEAT = UV1 + (size_t)BN*256;                 // BN*512
  float* UV2  = FEAT + (size_t)BN*512;                // BN*512
  float* H1   = UV2 + (size_t)BN*512;                 // NPTS*KNN*128 floats (10.49M) - knn scratch aliases
  float* PDd  = H1;                                   // NPART*BN*KNN floats (2.62M)
  int*   OUTB = (int*)(H1 + (size_t)4*1024*1024);     // BN*NPART*SLOTS ints (3.15M)
  int*   CNTb = (int*)(H1 + (size_t)8*1024*1024);     // BN*NPART ints
  int*   IDXF = (int*)(H1 + (size_t)NPTS*KNN*128);    // BN*KNN
  int*   IDXX = IDXF + (size_t)BN*KNN;                // BN*KNN
  float* WEFF1= (float*)(IDXX + (size_t)BN*KNN);      // 64*256
  float* WT2  = WEFF1 + 64*256;                       // 128*128
  float* WEFF2= WT2 + 128*128;                        // 128*512
  float* W3T  = WEFF2 + 128*512;                      // 512*1024
  float* BUV1 = W3T + 512*1024;                       // 256
  float* BUV2 = BUV1 + 256;                           // 512
  int*   SIDX = (int*)(BUV2 + 512);                   // NB*32
  int*   NIDX = SIDX + NB*32;                         // NB*32*8
  float* ACC  = (float*)(NIDX + NB*32*8);             // 8
  float* THR  = ACC + 8;                              // BN
  int*   QUO  = (int*)(THR + BN);                     // BN

  prep_weights<<<2048, 256, 0, stream>>>(wdg1, bdg1, wdg2, wsn1, bsn1, w3,
                                         WEFF1, WT2, WEFF2, W3T, BUV1, BUV2);

  auto run_knn = [&](auto chTag, const float* XT, const float* XX, int* IDX) {
    constexpr int CH  = decltype(chTag)::value;
    constexpr int CHP = (CH == 3) ? 4 : CH;
    knn_pass1<CH,CHP><<<dim3(BN/256, NPART), 256, 0, stream>>>(XT, XX, PDd);
    knn_merge_thr<<<BN/256, 256, 0, stream>>>(PDd, THR, QUO);
    knn_recover<CH,CHP><<<dim3(BN/256, NPART), 256, 0, stream>>>(XT, XX, THR, QUO, OUTB, CNTb);
    knn_stitch<<<BN/256, 256, 0, stream>>>(OUTB, CNTb, IDX);
  };

  auto run_cloud = [&](const float* xyz, float* emb) {
    pack_xyz<<<BN/256, 256, 0, stream>>>(xyz, XTP, XXP);
    conv12<<<BN/4, 256, 0, stream>>>(xyz, w1, b1, w2, b2, XT2, XX2);
    run_knn(std::integral_constant<int,64>{}, XT2, XX2, IDXF);
    run_knn(std::integral_constant<int,3>{},  XTP, XXP, IDXX);
    gemm_pm<false,false><<<dim3(BN/128, 2), 256, 0, stream>>>(
        WEFF1, 256, 64, XT2, 64, 0, BUV1, UV1, 256, 0);
    for (int bb = 0; bb < NB; ++bb) {
      gather_h1<<<NPTS, 256, 0, stream>>>(UV1, IDXF, H1, FEAT, bb);
      dg2_gemm<<<NPTS*KNN/80, 256, 0, stream>>>(WT2, H1, bdg2, FEAT, bb);
    }
    gemm_pm<false,false><<<dim3(BN/128, 4), 256, 0, stream>>>(
        WEFF2, 512, 128, FEAT, 512, 128, BUV2, UV2, 512, 0);
    sn_gather<<<BN/4, 256, 0, stream>>>(UV2, IDXX, FEAT);
    gemm_pm<true,true><<<dim3(BN/128, 8), 256, 0, stream>>>(
        W3T, 1024, 512, FEAT, 512, 0, b3, emb, 0, 0);
  };

  float* emb_s = out;
  float* emb_t = out + (size_t)BN*1024;
  run_cloud(src, emb_s);
  run_cloud(tgt, emb_t);

  hipMemsetAsync(ACC, 0, 8*sizeof(float), stream);
  fps_kernel<<<NB, 256, 0, stream>>>(src, SIDX);
  kfn_kernel<<<1, 128, 0, stream>>>(src, SIDX, NIDX);
  trip_kernel<<<NB*32, 256, 0, stream>>>(emb_s, emb_t, SIDX, NIDX, ACC);
  stats_kernel<<<BN/64, 256, 0, stream>>>(emb_s, emb_t, ACC);
  finalize_kernel<<<1, 64, 0, stream>>>(ACC, out + (size_t)2*BN*1024);
}

// Round 4
// 2296.279 us; speedup vs baseline: 1.5011x; 1.5011x over previous
//
#include <hip/hip_runtime.h>
#include <cstdint>

#define NB 4
#define NPTS 4096
#define KNN 20
#define BN (NB*NPTS)   // 16384

__device__ __forceinline__ float lrelu_f(float x) { return x > 0.f ? x : 0.2f * x; }

__device__ __forceinline__ float med3f(float c, float lo, float hi) {
#if defined(__has_builtin)
#if __has_builtin(__builtin_amdgcn_fmed3f)
  return __builtin_amdgcn_fmed3f(c, lo, hi);
#else
  return fminf(fmaxf(c, lo), hi);
#endif
#else
  return fminf(fmaxf(c, lo), hi);
#endif
}

// ---------------------------------------------------------------- prep weights
__global__ __launch_bounds__(256) void prep_weights(
    const float* __restrict__ wdg1, const float* __restrict__ bdg1,
    const float* __restrict__ wdg2,
    const float* __restrict__ wsn1, const float* __restrict__ bsn1,
    const float* __restrict__ w3,
    float* __restrict__ WEFF1, float* __restrict__ WT2,
    float* __restrict__ WEFF2, float* __restrict__ W3T,
    float* __restrict__ BUV1, float* __restrict__ BUV2)
{
  int i = blockIdx.x * 256 + threadIdx.x;
  if (i < 512*1024) { int c = i >> 10, o = i & 1023; W3T[i] = w3[o*512 + c]; }
  if (i < 64*256) {
    int c = i >> 8, r = i & 255;
    WEFF1[i] = (r < 128) ? wdg1[r*128 + c]
                         : (wdg1[(r-128)*128 + 64 + c] - wdg1[(r-128)*128 + c]);
  }
  if (i < 128*128) { int c = i >> 7, o = i & 127; WT2[i] = wdg2[o*128 + c]; }
  if (i < 128*512) {
    int c = i >> 9, r = i & 511;
    WEFF2[i] = (r < 256) ? wsn1[r*256 + c]
                         : (wsn1[(r-256)*256 + 128 + c] - wsn1[(r-256)*256 + c]);
  }
  if (i < 256) BUV1[i] = (i < 128) ? 0.f : bdg1[i-128];
  if (i < 512) BUV2[i] = (i < 256) ? 0.f : bsn1[i-256];
}

// ---------------------------------------------------------------- pack xyz -> float4 (x,y,z,xx)
__global__ __launch_bounds__(256) void pack_xyz(
    const float* __restrict__ xyz, float4* __restrict__ XTP4)
{
  int i = blockIdx.x * 256 + threadIdx.x;
  if (i >= BN) return;
  int b = i >> 12, n = i & (NPTS-1);
  const float* p = xyz + (size_t)b*3*NPTS;
  float x = p[n], y = p[NPTS+n], z = p[2*NPTS+n];
  float4 v; v.x = x; v.y = y; v.z = z; v.w = x*x + y*y + z*z;
  XTP4[i] = v;
}

// ---------------------------------------------------------------- conv1 + conv2 fused (3->64->64), point-major out + sqnorm
__global__ __launch_bounds__(256) void conv12(
    const float* __restrict__ xyz,
    const float* __restrict__ w1, const float* __restrict__ b1,
    const float* __restrict__ w2, const float* __restrict__ b2,
    float* __restrict__ XT2, float* __restrict__ XX2)
{
  __shared__ float w2t[64*65];
  __shared__ float h1s[4][64];
  int tid = threadIdx.x;
  for (int i = tid; i < 4096; i += 256) {
    int o = i >> 6, c = i & 63;
    w2t[c*65 + o] = w2[i];
  }
  int g = tid >> 6, o = tid & 63;
  int pt = blockIdx.x*4 + g;
  int b = pt >> 12, n = pt & (NPTS-1);
  const float* p = xyz + (size_t)b*3*NPTS;
  float x = p[n], y = p[NPTS+n], z = p[2*NPTS+n];
  float h1 = b1[o] + w1[o*3]*x + w1[o*3+1]*y + w1[o*3+2]*z;
  h1 = lrelu_f(h1);
  __syncthreads();
  h1s[g][o] = h1;
  __syncthreads();
  float acc = b2[o];
  #pragma unroll
  for (int c = 0; c < 64; ++c) acc = fmaf(w2t[c*65+o], h1s[g][c], acc);
  acc = lrelu_f(acc);
  XT2[(size_t)pt*64 + o] = acc;
  float v = acc*acc;
  #pragma unroll
  for (int s = 32; s > 0; s >>= 1) v += __shfl_down(v, s, 64);
  if (o == 0) XX2[pt] = v;
}

// ---------------------------------------------------------------- distance GEMM (per batch): D[q][j] = xx_j - 2*dot(q,j)
__global__ __launch_bounds__(256) void dist_gemm(
    const float* __restrict__ XQ,   // batch slice of XT2, [4096][64]
    const float* __restrict__ XXb,  // batch slice of XX2, [4096]
    float* __restrict__ D)          // [4096][4096]
{
  __shared__ float Qs[16][132];
  __shared__ float Xs[16][132];
  int tid = threadIdx.x;
  int rg = tid & 15, cg = tid >> 4;
  int q0 = blockIdx.y * 128, j0 = blockIdx.x * 128;
  float acc[8][8];
  #pragma unroll
  for (int u = 0; u < 8; ++u)
    #pragma unroll
    for (int v = 0; v < 8; ++v) acc[u][v] = 0.f;

  for (int c0 = 0; c0 < 64; c0 += 16) {
    #pragma unroll
    for (int i = 0; i < 8; ++i) {
      int idx = tid + i*256;
      int kk = idx & 15, p = idx >> 4;
      Qs[kk][p] = XQ[(size_t)(q0+p)*64 + c0 + kk];
      Xs[kk][p] = XQ[(size_t)(j0+p)*64 + c0 + kk];
    }
    __syncthreads();
    #pragma unroll
    for (int kk = 0; kk < 16; ++kk) {
      float a[8], bb[8];
      #pragma unroll
      for (int u = 0; u < 8; ++u) a[u] = Qs[kk][rg*8+u];
      #pragma unroll
      for (int v = 0; v < 8; ++v) bb[v] = Xs[kk][cg*8+v];
      #pragma unroll
      for (int u = 0; u < 8; ++u)
        #pragma unroll
        for (int v = 0; v < 8; ++v) acc[u][v] = fmaf(a[u], bb[v], acc[u][v]);
    }
    __syncthreads();
  }
  float xxv[8];
  #pragma unroll
  for (int v = 0; v < 8; ++v) xxv[v] = XXb[j0 + cg*8 + v];
  #pragma unroll
  for (int u = 0; u < 8; ++u) {
    float* po = D + (size_t)(q0 + rg*8 + u)*NPTS + j0 + cg*8;
    #pragma unroll
    for (int v = 0; v < 8; ++v) po[v] = fmaf(-2.f, acc[u][v], xxv[v]);
  }
}

// ---------------------------------------------------------------- knn select: one wave per query, exact top-20 indices
// FEAT_MODE: distances read from D (per-batch). else: recomputed from XTP4 (xyz).
template<bool FEAT_MODE>
__global__ __launch_bounds__(256) void knn_select(
    const float* __restrict__ D, const float4* __restrict__ XTP4,
    int batch, int* __restrict__ IDX)
{
  int lane = threadIdx.x & 63;
  int ql = blockIdx.x*4 + (threadIdx.x >> 6);   // query local to batch
  int qg = batch*NPTS + ql;                     // global point id
  const float4* drow4 = FEAT_MODE ? (const float4*)(D + (size_t)ql*NPTS) : nullptr;
  const float4* Xb4 = XTP4 + (size_t)batch*NPTS;
  float qx = 0.f, qy = 0.f, qz = 0.f;
  if (!FEAT_MODE) { float4 qp = XTP4[qg]; qx = qp.x; qy = qp.y; qz = qp.z; }

  auto key3 = [&](float4 p) -> float {
    float dot = qx*p.x;
    dot = fmaf(qy, p.y, dot);
    dot = fmaf(qz, p.z, dot);
    return fmaf(-2.f, dot, p.w);
  };
  auto getd4 = [&](int t) -> float4 {
    if (FEAT_MODE) {
      return drow4[t*64 + lane];
    } else {
      int jb = t*256 + lane*4;
      float4 r;
      r.x = key3(Xb4[jb+0]);
      r.y = key3(Xb4[jb+1]);
      r.z = key3(Xb4[jb+2]);
      r.w = key3(Xb4[jb+3]);
      return r;
    }
  };

  // ---- phase 1: per-lane top-20 distances (values only) over 64 candidates
  float bd[KNN];
  #pragma unroll
  for (int t = 0; t < KNN; ++t) bd[t] = 1e30f;
  for (int t = 0; t < 16; ++t) {
    float4 dv = getd4(t);
    float ds[4] = {dv.x, dv.y, dv.z, dv.w};
    #pragma unroll
    for (int e = 0; e < 4; ++e) {
      float cd = ds[e];
      #pragma unroll
      for (int s = KNN-1; s >= 1; --s) bd[s] = med3f(cd, bd[s-1], bd[s]);
      bd[0] = fminf(bd[0], cd);
    }
  }

  // ---- phase 2: wave-level 20th-smallest value (thr)
  float thr = 1e30f;
  {
    int total = 0;
    #pragma unroll 1
    for (int r = 0; r < KNN; ++r) {
      float m = bd[0];
      #pragma unroll
      for (int k = 1; k < 64; k <<= 1) m = fminf(m, __shfl_xor(m, k, 64));
      unsigned long long bal = __ballot(bd[0] == m);
      total += __popcll(bal);
      if (total >= KNN) { thr = m; break; }
      if (bd[0] == m) {
        #pragma unroll
        for (int s = 0; s < KNN-1; ++s) bd[s] = bd[s+1];
        bd[KNN-1] = 1e30f;
      }
    }
  }

  // ---- phase 3: rescan, emit strict (d<thr) via ballot-compaction; ties by smallest j
  unsigned long long lml = (1ull << lane) - 1ull;
  int S = 0;
  int myj = 0x7fffffff;
  for (int t = 0; t < 16; ++t) {
    float4 dv = getd4(t);
    float ds[4] = {dv.x, dv.y, dv.z, dv.w};
    int jb = t*256 + lane*4;
    #pragma unroll
    for (int e = 0; e < 4; ++e) {
      float d = ds[e];
      int j = jb + e;
      bool ps = d < thr;
      unsigned long long mk = __ballot(ps);
      int pos = S + __popcll(mk & lml);
      if (ps && pos < KNN) IDX[(size_t)qg*KNN + pos] = j;
      S += __popcll(mk);
      if (d == thr && j < myj) myj = j;
    }
  }
  int need = KNN - S;
  if (need == 1) {
    int mn = myj;
    #pragma unroll
    for (int k = 1; k < 64; k <<= 1) mn = min(mn, __shfl_xor(mn, k, 64));
    if (lane == 0) IDX[(size_t)qg*KNN + S] = mn;
  } else if (need > 1) {
    // degenerate (duplicate distances) — rare; serial scan by lane 0
    if (lane == 0) {
      int taken = 0;
      for (int j = 0; j < NPTS && taken < need; ++j) {
        float d;
        if (FEAT_MODE) d = D[(size_t)ql*NPTS + j];
        else           d = key3(Xb4[j]);
        if (d == thr) { IDX[(size_t)qg*KNN + S + taken] = j; ++taken; }
      }
    }
  }
}

// ---------------------------------------------------------------- generic point-major GEMM: Out = act(Wt^T-ish @ F + bias)
template<bool LRELU_, bool CM>
__global__ __launch_bounds__(256) void gemm_pm(
    const float* __restrict__ Wt, int Mtot, int KT,
    const float* __restrict__ F, int fstride, int foff,
    const float* __restrict__ bias,
    float* __restrict__ Out, int ostride, int ooff)
{
  __shared__ float Ws[16][128];
  __shared__ float Fs[16][132];
  int tid = threadIdx.x;
  int rg = tid & 15, cg = tid >> 4;
  int rt = blockIdx.y * 128, ct = blockIdx.x * 128;
  float acc[8][8];
  #pragma unroll
  for (int u = 0; u < 8; ++u)
    #pragma unroll
    for (int v = 0; v < 8; ++v) acc[u][v] = 0.f;

  for (int c0 = 0; c0 < KT; c0 += 16) {
    #pragma unroll
    for (int i = 0; i < 8; ++i) {
      int idx = tid + i*256;
      int kk = idx >> 7, r = idx & 127;
      Ws[kk][r] = Wt[(size_t)(c0+kk)*Mtot + rt + r];
    }
    #pragma unroll
    for (int i = 0; i < 8; ++i) {
      int idx = tid + i*256;
      int kk = idx & 15, p = idx >> 4;
      Fs[kk][p] = F[(size_t)(ct+p)*fstride + foff + c0 + kk];
    }
    __syncthreads();
    #pragma unroll
    for (int kk = 0; kk < 16; ++kk) {
      float a[8], bb[8];
      #pragma unroll
      for (int u = 0; u < 8; ++u) a[u] = Ws[kk][rg*8+u];
      #pragma unroll
      for (int v = 0; v < 8; ++v) bb[v] = Fs[kk][cg*8+v];
      #pragma unroll
      for (int u = 0; u < 8; ++u)
        #pragma unroll
        for (int v = 0; v < 8; ++v) acc[u][v] = fmaf(a[u], bb[v], acc[u][v]);
    }
    __syncthreads();
  }
  #pragma unroll
  for (int u = 0; u < 8; ++u) {
    float bv = bias[rt + rg*8 + u];
    #pragma unroll
    for (int v = 0; v < 8; ++v) {
      float val = acc[u][v] + bv;
      if (LRELU_) val = lrelu_f(val);
      acc[u][v] = val;
    }
  }
  if (CM) {
    int b = ct >> 12, n0 = ct & (NPTS-1);
    #pragma unroll
    for (int u = 0; u < 8; ++u) {
      int r = rt + rg*8 + u;
      float* po = Out + ((size_t)b*Mtot + r)*NPTS + n0 + cg*8;
      #pragma unroll
      for (int v = 0; v < 8; ++v) po[v] = acc[u][v];
    }
  } else {
    #pragma unroll
    for (int v = 0; v < 8; ++v) {
      int pt = ct + cg*8 + v;
      float* po = Out + (size_t)pt*ostride + ooff + rt + rg*8;
      #pragma unroll
      for (int u = 0; u < 8; ++u) po[u] = acc[u][v];
    }
  }
}

// ---------------------------------------------------------------- gather H1 = lrelu(U1[j] + V1[n]) (per batch), also x1 = max_k
__global__ __launch_bounds__(256) void gather_h1(
    const float* __restrict__ UV1, const int* __restrict__ IDXF,
    float* __restrict__ H1, float* __restrict__ FEAT, int batch)
{
  int n = blockIdx.x;
  int tid = threadIdx.x;
  size_t ptg = (size_t)batch*NPTS + n;
  __shared__ int js[KNN];
  if (tid < KNN) js[tid] = IDXF[ptg*KNN + tid];
  __syncthreads();
  int c = tid & 127, k0 = tid >> 7;
  float vv = UV1[ptg*256 + 128 + c];
  const float* Ub = UV1 + ((size_t)batch*NPTS)*256;
  float* Hb = H1 + (size_t)n*KNN*128;
  float mx = -1e30f;
  for (int kk = k0; kk < KNN; kk += 2) {
    int j = js[kk];
    float h = lrelu_f(Ub[(size_t)j*256 + c] + vv);
    Hb[kk*128 + c] = h;
    mx = fmaxf(mx, h);
  }
  __shared__ float m2[2][128];
  m2[k0][c] = mx;
  __syncthreads();
  if (tid < 128) FEAT[ptg*512 + tid] = fmaxf(m2[0][tid], m2[1][tid]);
}

// ---------------------------------------------------------------- dg2 GEMM with lrelu + 20-group max epilogue -> x2
__global__ __launch_bounds__(256) void dg2_gemm(
    const float* __restrict__ Wt2, const float* __restrict__ H1,
    const float* __restrict__ bias, float* __restrict__ FEAT, int batch)
{
  __shared__ float Ws[16][128];
  __shared__ float Fs[16][84];
  __shared__ float mb[16][132];
  int tid = threadIdx.x;
  int rg = tid & 15, cg = tid >> 4;
  int ct = blockIdx.x * 80;
  float acc[8][5];
  #pragma unroll
  for (int u = 0; u < 8; ++u)
    #pragma unroll
    for (int v = 0; v < 5; ++v) acc[u][v] = 0.f;

  for (int c0 = 0; c0 < 128; c0 += 16) {
    #pragma unroll
    for (int i = 0; i < 8; ++i) {
      int idx = tid + i*256;
      int kk = idx >> 7, r = idx & 127;
      Ws[kk][r] = Wt2[(c0+kk)*128 + r];
    }
    #pragma unroll
    for (int i = 0; i < 5; ++i) {
      int idx = tid + i*256;
      int kk = idx & 15, p = idx >> 4;
      Fs[kk][p] = H1[(size_t)(ct+p)*128 + c0 + kk];
    }
    __syncthreads();
    #pragma unroll
    for (int kk = 0; kk < 16; ++kk) {
      float a[8], bb[5];
      #pragma unroll
      for (int u = 0; u < 8; ++u) a[u] = Ws[kk][rg*8+u];
      #pragma unroll
      for (int v = 0; v < 5; ++v) bb[v] = Fs[kk][cg*5+v];
      #pragma unroll
      for (int u = 0; u < 8; ++u)
        #pragma unroll
        for (int v = 0; v < 5; ++v) acc[u][v] = fmaf(a[u], bb[v], acc[u][v]);
    }
    __syncthreads();
  }
  #pragma unroll
  for (int u = 0; u < 8; ++u) {
    int r = rg*8+u;
    float bv = bias[r];
    float m = -1e30f;
    #pragma unroll
    for (int v = 0; v < 5; ++v) m = fmaxf(m, lrelu_f(acc[u][v] + bv));
    mb[cg][r] = m;
  }
  __syncthreads();
  if ((cg & 3) == 0) {
    int g = cg >> 2;
    size_t pt = (size_t)batch*NPTS + blockIdx.x*4 + g;
    #pragma unroll
    for (int u = 0; u < 8; ++u) {
      int r = rg*8+u;
      float m = fmaxf(fmaxf(mb[cg][r], mb[cg+1][r]), fmaxf(mb[cg+2][r], mb[cg+3][r]));
      FEAT[pt*512 + 128 + r] = m;
    }
  }
}

// ---------------------------------------------------------------- sn block: x3 = max_k lrelu(U2[j] + V2[n])
__global__ __launch_bounds__(256) void sn_gather(
    const float* __restrict__ UV2, const int* __restrict__ IDXX,
    float* __restrict__ FEAT)
{
  int tid = threadIdx.x;   // channel 0..255
  int p0 = blockIdx.x * 4;
  for (int pp = 0; pp < 4; ++pp) {
    size_t pt = (size_t)(p0 + pp);
    size_t bb = (size_t)((p0+pp) >> 12) << 12;
    float v = UV2[pt*512 + 256 + tid];
    float m = -1e30f;
    for (int k = 0; k < KNN; ++k) {
      int j = IDXX[pt*KNN + k];
      float h = lrelu_f(UV2[(bb + j)*512 + tid] + v);
      m = fmaxf(m, h);
    }
    FEAT[pt*512 + 256 + tid] = m;
  }
}

// ---------------------------------------------------------------- farthest point sampling (per batch)
__global__ __launch_bounds__(256) void fps_kernel(
    const float* __restrict__ xyz, int* __restrict__ SIDX)
{
  int b = blockIdx.x, tid = threadIdx.x;
  const float* p = xyz + (size_t)b*3*NPTS;
  __shared__ float dist[NPTS];
  __shared__ float rmax[256];
  __shared__ int   ridx[256];
  __shared__ int   curf;
  for (int i = tid; i < NPTS; i += 256) dist[i] = 1e10f;
  if (tid == 0) curf = 0;
  __syncthreads();
  for (int it = 0; it < 32; ++it) {
    int far = curf;
    if (tid == 0) SIDX[b*32 + it] = far;
    float cx = p[far], cy = p[NPTS+far], cz = p[2*NPTS+far];
    float lm = -1e30f; int li = 0;
    for (int i = tid; i < NPTS; i += 256) {
      float dx = p[i]-cx, dy = p[NPTS+i]-cy, dz = p[2*NPTS+i]-cz;
      float d = dx*dx + dy*dy + dz*dz;
      float dm = fminf(dist[i], d);
      dist[i] = dm;
      if (dm > lm) { lm = dm; li = i; }
    }
    rmax[tid] = lm; ridx[tid] = li;
    __syncthreads();
    for (int s = 128; s > 0; s >>= 1) {
      if (tid < s) {
        float a = rmax[tid], bv = rmax[tid+s];
        int ia = ridx[tid], ib = ridx[tid+s];
        if (bv > a || (bv == a && ib < ia)) { rmax[tid] = bv; ridx[tid] = ib; }
      }
      __syncthreads();
    }
    if (tid == 0) curf = ridx[0];
    __syncthreads();
  }
}

// ---------------------------------------------------------------- k-farthest (8) among 32 samples
__global__ __launch_bounds__(128) void kfn_kernel(
    const float* __restrict__ xyz, const int* __restrict__ SIDX,
    int* __restrict__ NIDX)
{
  int tid = threadIdx.x;     // 0..127
  int b = tid >> 5, i = tid & 31;
  const float* p = xyz + (size_t)b*3*NPTS;
  __shared__ float sx[4][32], sy[4][32], sz[4][32];
  {
    int si = SIDX[b*32 + i];
    sx[b][i] = p[si]; sy[b][i] = p[NPTS+si]; sz[b][i] = p[2*NPTS+si];
  }
  __syncthreads();
  float xi = sx[b][i], yi = sy[b][i], zi = sz[b][i];
  float xxi = xi*xi + yi*yi + zi*zi;
  float bd[8]; int bi_[8];
  #pragma unroll
  for (int t = 0; t < 8; ++t) { bd[t] = -1e30f; bi_[t] = 0; }
  for (int j = 0; j < 32; ++j) {
    float xj = sx[b][j], yj = sy[b][j], zj = sz[b][j];
    float xxj = xj*xj + yj*yj + zj*zj;
    float d = xxi - 2.f*(xi*xj + yi*yj + zi*zj) + xxj;
    if (d > bd[7]) {
      float cd = d; int ci = j;
      #pragma unroll
      for (int t = 0; t < 8; ++t) {
        bool sw = bd[t] < cd;       // descending
        float nv = sw ? cd : bd[t];
        int   ni = sw ? ci : bi_[t];
        float ov = sw ? bd[t] : cd;
        int   oi = sw ? bi_[t] : ci;
        bd[t] = nv; bi_[t] = ni; cd = ov; ci = oi;
      }
    }
  }
  size_t o = (size_t)(b*32 + i)*8;
  #pragma unroll
  for (int t = 0; t < 8; ++t) NIDX[o+t] = bi_[t];
}

// ---------------------------------------------------------------- triplet terms
__global__ __launch_bounds__(256) void trip_kernel(
    const float* __restrict__ es0, const float* __restrict__ et0,
    const int* __restrict__ SIDX, const int* __restrict__ NIDX,
    float* __restrict__ ACC)
{
  int bi_ = blockIdx.x; int b = bi_ >> 5;
  int tid = threadIdx.x;
  __shared__ int js[8];
  __shared__ int ssi;
  if (tid == 0) ssi = SIDX[bi_];
  if (tid < 8) js[tid] = SIDX[b*32 + NIDX[bi_*8 + tid]];
  __syncthreads();
  int si = ssi;
  const float* es = es0 + (size_t)b*1024*NPTS;
  const float* et = et0 + (size_t)b*1024*NPTS;
  float sp = 0.f, sn = 0.f;
  for (int c = tid; c < 1024; c += 256) {
    const float* erow = et + (size_t)c*NPTS;
    float s = es[(size_t)c*NPTS + si];
    float d0 = s - erow[si]; sp += d0*d0;
    #pragma unroll
    for (int t = 0; t < 8; ++t) { float d1 = s - erow[js[t]]; sn += d1*d1; }
  }
  __shared__ float r1[256], r2[256];
  r1[tid] = sp; r2[tid] = sn; __syncthreads();
  for (int s2 = 128; s2 > 0; s2 >>= 1) {
    if (tid < s2) { r1[tid] += r1[tid+s2]; r2[tid] += r2[tid+s2]; }
    __syncthreads();
  }
  if (tid == 0) {
    float dp = r1[0] * (1.f/1024.f);
    float dn = r2[0] * (1.f/8192.f);
    float tr = fmaxf(0.f, 1.f - dn/(1.f + dp));
    atomicAdd(&ACC[0], tr);
  }
}

// ---------------------------------------------------------------- norms + mse + mae
__global__ __launch_bounds__(256) void stats_kernel(
    const float* __restrict__ es0, const float* __restrict__ et0,
    float* __restrict__ ACC)
{
  int tid = threadIdx.x;
  int p = tid & 63, g = tid >> 6;
  int pt0 = blockIdx.x * 64;
  int b = pt0 >> 12, n0 = pt0 & (NPTS-1);
  const float* es = es0 + (size_t)b*1024*NPTS + n0;
  const float* et = et0 + (size_t)b*1024*NPTS + n0;
  float ss = 0.f, tt = 0.f, sq = 0.f, ab = 0.f;
  for (int c = g; c < 1024; c += 4) {
    float s = es[(size_t)c*NPTS + p];
    float t = et[(size_t)c*NPTS + p];
    ss += s*s; tt += t*t;
    float d = s - t;
    sq += d*d; ab += fabsf(d);
  }
  __shared__ float rs[4][64], rt[4][64];
  __shared__ float red[256];
  rs[g][p] = ss; rt[g][p] = tt;
  red[tid] = sq;
  __syncthreads();
  for (int s2 = 128; s2 > 0; s2 >>= 1) {
    if (tid < s2) red[tid] += red[tid+s2];
    __syncthreads();
  }
  if (tid == 0) atomicAdd(&ACC[3], red[0]);
  __syncthreads();
  red[tid] = ab; __syncthreads();
  for (int s2 = 128; s2 > 0; s2 >>= 1) {
    if (tid < s2) red[tid] += red[tid+s2];
    __syncthreads();
  }
  if (tid == 0) atomicAdd(&ACC[4], red[0]);
  if (tid < 64) {
    float a = sqrtf(rs[0][tid]+rs[1][tid]+rs[2][tid]+rs[3][tid]) - 1.f;
    float c = sqrtf(rt[0][tid]+rt[1][tid]+rt[2][tid]+rt[3][tid]) - 1.f;
    float av = a*a, cv = c*c;
    #pragma unroll
    for (int s2 = 32; s2 > 0; s2 >>= 1) {
      av += __shfl_down(av, s2, 64);
      cv += __shfl_down(cv, s2, 64);
    }
    if (tid == 0) { atomicAdd(&ACC[1], av); atomicAdd(&ACC[2], cv); }
  }
}

// ---------------------------------------------------------------- finalize scalars
__global__ void finalize_kernel(const float* __restrict__ ACC, float* __restrict__ o3) {
  if (threadIdx.x == 0 && blockIdx.x == 0) {
    float ln1 = sqrtf(ACC[1] * (1.f/16384.f));
    float ln2 = sqrtf(ACC[2] * (1.f/16384.f));
    o3[0] = ACC[0]*(1.f/128.f) + (ln1 + ln2)*0.5f*0.03f;
    o3[1] = ACC[3] * (1.f/4194304.f);   // mean((s-t)^2)*B
    o3[2] = ACC[4] * (1.f/4194304.f);   // mean(|s-t|)*B
  }
}

// ================================================================ host
extern "C" void kernel_launch(void* const* d_in, const int* in_sizes, int n_in,
                              void* d_out, int out_size, void* d_ws, size_t ws_size,
                              hipStream_t stream) {
  (void)in_sizes; (void)n_in; (void)out_size; (void)ws_size;
  const float* src  = (const float*)d_in[0];
  const float* tgt  = (const float*)d_in[1];
  const float* w1   = (const float*)d_in[2];
  const float* b1   = (const float*)d_in[3];
  const float* w2   = (const float*)d_in[4];
  const float* b2   = (const float*)d_in[5];
  const float* wdg1 = (const float*)d_in[6];
  const float* bdg1 = (const float*)d_in[7];
  const float* wdg2 = (const float*)d_in[8];
  const float* bdg2 = (const float*)d_in[9];
  const float* wsn1 = (const float*)d_in[10];
  const float* bsn1 = (const float*)d_in[11];
  const float* w3   = (const float*)d_in[12];
  const float* b3   = (const float*)d_in[13];
  float* out = (float*)d_out;

  float* ws = (float*)d_ws;
  float*  XTP  = ws;                                  // BN*4 (float4 x,y,z,xx)
  float*  XT2  = XTP + (size_t)BN*4;                  // BN*64
  float*  XX2  = XT2 + (size_t)BN*64;                 // BN
  float*  UV1  = XX2 + BN;                            // BN*256
  float*  FEAT = UV1 + (size_t)BN*256;                // BN*512
  float*  UV2  = FEAT + (size_t)BN*512;               // BN*512
  float*  Dbuf = FEAT;                                // 4096*4096 aliases FEAT+UV2 (dead when FEAT/UV2 live)
  float*  H1   = UV2 + (size_t)BN*512;                // NPTS*KNN*128
  int*    IDXF = (int*)(H1 + (size_t)NPTS*KNN*128);   // BN*KNN
  int*    IDXX = IDXF + (size_t)BN*KNN;               // BN*KNN
  float*  WEFF1= (float*)(IDXX + (size_t)BN*KNN);     // 64*256
  float*  WT2  = WEFF1 + 64*256;                      // 128*128
  float*  WEFF2= WT2 + 128*128;                       // 128*512
  float*  W3T  = WEFF2 + 128*512;                     // 512*1024
  float*  BUV1 = W3T + 512*1024;                      // 256
  float*  BUV2 = BUV1 + 256;                          // 512
  int*    SIDX = (int*)(BUV2 + 512);                  // NB*32
  int*    NIDX = SIDX + NB*32;                        // NB*32*8
  float*  ACC  = (float*)(NIDX + NB*32*8);            // 8

  prep_weights<<<2048, 256, 0, stream>>>(wdg1, bdg1, wdg2, wsn1, bsn1, w3,
                                         WEFF1, WT2, WEFF2, W3T, BUV1, BUV2);

  auto run_cloud = [&](const float* xyz, float* emb) {
    pack_xyz<<<BN/256, 256, 0, stream>>>(xyz, (float4*)XTP);
    conv12<<<BN/4, 256, 0, stream>>>(xyz, w1, b1, w2, b2, XT2, XX2);
    // KNN: per batch, distance GEMM (feat) + wave-per-query selection (feat & xyz)
    for (int bb = 0; bb < NB; ++bb) {
      dist_gemm<<<dim3(32,32), 256, 0, stream>>>(
          XT2 + (size_t)bb*NPTS*64, XX2 + (size_t)bb*NPTS, Dbuf);
      knn_select<true><<<NPTS/4, 256, 0, stream>>>(Dbuf, (const float4*)XTP, bb, IDXF);
      knn_select<false><<<NPTS/4, 256, 0, stream>>>(nullptr, (const float4*)XTP, bb, IDXX);
    }
    gemm_pm<false,false><<<dim3(BN/128, 2), 256, 0, stream>>>(
        WEFF1, 256, 64, XT2, 64, 0, BUV1, UV1, 256, 0);
    for (int bb = 0; bb < NB; ++bb) {
      gather_h1<<<NPTS, 256, 0, stream>>>(UV1, IDXF, H1, FEAT, bb);
      dg2_gemm<<<NPTS*KNN/80, 256, 0, stream>>>(WT2, H1, bdg2, FEAT, bb);
    }
    gemm_pm<false,false><<<dim3(BN/128, 4), 256, 0, stream>>>(
        WEFF2, 512, 128, FEAT, 512, 128, BUV2, UV2, 512, 0);
    sn_gather<<<BN/4, 256, 0, stream>>>(UV2, IDXX, FEAT);
    gemm_pm<true,true><<<dim3(BN/128, 8), 256, 0, stream>>>(
        W3T, 1024, 512, FEAT, 512, 0, b3, emb, 0, 0);
  };

  float* emb_s = out;
  float* emb_t = out + (size_t)BN*1024;
  run_cloud(src, emb_s);
  run_cloud(tgt, emb_t);

  hipMemsetAsync(ACC, 0, 8*sizeof(float), stream);
  fps_kernel<<<NB, 256, 0, stream>>>(src, SIDX);
  kfn_kernel<<<1, 128, 0, stream>>>(src, SIDX, NIDX);
  trip_kernel<<<NB*32, 256, 0, stream>>>(emb_s, emb_t, SIDX, NIDX, ACC);
  stats_kernel<<<BN/64, 256, 0, stream>>>(emb_s, emb_t, ACC);
  finalize_kernel<<<1, 64, 0, stream>>>(ACC, out + (size_t)2*BN*1024);
}